// Round 4
// baseline (225.941 us; speedup 1.0000x reference)
//
#include <hip/hip_runtime.h>
#include <math.h>
#include <stdint.h>

#define C        128
#define KCODES   1024
#define TPB      256
#define ROWS_PB  256
#define NCHUNK   32
#define NCHUNKS  (KCODES / NCHUNK)          // 32
#define BSTRIDE  272                        // padded LDS row stride (bytes)
#define CHUNK_BYTES (NCHUNK * 2 * BSTRIDE)  // hi+lo = 17408
#define BIGF     1024.0f
#define EPS_TRIG 0.0625f

typedef __attribute__((ext_vector_type(8))) short bf16x8_t;
typedef __attribute__((ext_vector_type(4))) float f32x4_t;
#define MFMA_BF16 __builtin_amdgcn_mfma_f32_16x16x32_bf16

static __device__ __forceinline__ uint32_t bf16_rne(float f) {
    uint32_t u = __float_as_uint(f);
    return (u + 0x7FFFu + ((u >> 16) & 1u)) >> 16;
}
static __device__ __forceinline__ float bf16_hi_f(float f) {
    return __uint_as_float(bf16_rne(f) << 16);
}

// insert (qv,kc) into a sorted top-3 (lex order: value bits, then code)
static __device__ __forceinline__ void ins3(uint32_t qv, int kc, uint32_t* q_, int* k_) {
    bool b0 = (qv < q_[0]) || (qv == q_[0] && kc < k_[0]);
    bool b1 = (qv < q_[1]) || (qv == q_[1] && kc < k_[1]);
    bool b2 = (qv < q_[2]) || (qv == q_[2] && kc < k_[2]);
    if (b0)      { q_[2]=q_[1]; k_[2]=k_[1]; q_[1]=q_[0]; k_[1]=k_[0]; q_[0]=qv; k_[0]=kc; }
    else if (b1) { q_[2]=q_[1]; k_[2]=k_[1]; q_[1]=qv;   k_[1]=kc; }
    else if (b2) { q_[2]=qv;   k_[2]=kc; }
}

// ---------------- prep: split codebook into bf16 hi/lo ----------------
__global__ void cb_split_kernel(const float* __restrict__ cb,
                                uint16_t* __restrict__ cbh,
                                uint16_t* __restrict__ cbl) {
    int i = blockIdx.x * blockDim.x + threadIdx.x;
    if (i >= KCODES * C) return;
    float f = cb[i];
    uint32_t h = bf16_rne(f);
    float lo = f - __uint_as_float(h << 16);
    cbh[i] = (uint16_t)h;
    cbl[i] = (uint16_t)bf16_rne(lo);
}

// ---------------- prep: ||c||^2 ----------------
__global__ void cbsq_kernel(const float* __restrict__ cb, float* __restrict__ cbsq) {
    const int k = blockIdx.x * blockDim.x + threadIdx.x;
    if (k >= KCODES) return;
    const float4* cp = (const float4*)(cb + (size_t)k * C);
    float sx = 0.f, sy = 0.f, sz = 0.f, sw = 0.f;
    #pragma unroll
    for (int i = 0; i < C / 4; ++i) {
        float4 v = cp[i];
        sx += v.x * v.x; sy += v.y * v.y;
        sz += v.z * v.z; sw += v.w * v.w;
    }
    cbsq[k] = (sx + sy) + (sz + sw);
}

// ---------------- main: MFMA distances, packed top-3, in-block finalize ----------------
__global__ __launch_bounds__(TPB, 1)
void vq_mfma2_kernel(const float* __restrict__ x,
                     const float* __restrict__ cb,
                     const uint16_t* __restrict__ cbh,
                     const uint16_t* __restrict__ cbl,
                     const float* __restrict__ cq,
                     float* __restrict__ out_codes,
                     float* __restrict__ out_fidx,
                     float* __restrict__ out_idx,
                     float* __restrict__ out_dist,
                     int rows)
{
    __shared__ __align__(16) uint8_t s_buf[2 * CHUNK_BYTES];   // 34816 B, double-buffered B chunks
    __shared__ float    s_cqb[2][NCHUNK];
    __shared__ float    s_rs[ROWS_PB];
    __shared__ int      s_kf[ROWS_PB];
    __shared__ uint32_t s_resq[ROWS_PB][3];
    __shared__ int      s_resk[ROWS_PB][3];

    const int t    = threadIdx.x;
    const int lane = t & 63;
    const int w    = t >> 6;        // wave 0..3
    const int ln   = lane & 15;
    const int quad = lane >> 4;
    const int rowblock = blockIdx.x * ROWS_PB;
    const int wbase    = w * 64;    // 64 rows per wave (4 rowgroups of 16)

    // ---- A fragments (bf16 hi/lo) straight from global; rs as by-product ----
    bf16x8_t ah[4][4], al[4][4];
    #pragma unroll
    for (int g = 0; g < 4; ++g) {
        int rowg = rowblock + wbase + g * 16 + ln;
        rowg = rowg < rows ? rowg : rows - 1;
        const float* xp = x + (size_t)rowg * C + quad * 8;
        float part = 0.f;
        #pragma unroll
        for (int kk = 0; kk < 4; ++kk) {
            float4 v0 = *(const float4*)(xp + kk * 32);
            float4 v1 = *(const float4*)(xp + kk * 32 + 4);
            float f[8] = {v0.x, v0.y, v0.z, v0.w, v1.x, v1.y, v1.z, v1.w};
            bf16x8_t hv, lv;
            #pragma unroll
            for (int j = 0; j < 8; ++j) {
                float fj = f[j];
                part = fmaf(fj, fj, part);
                uint32_t hb = bf16_rne(fj);
                hv[j] = (short)hb;
                float r = fj - __uint_as_float(hb << 16);
                lv[j] = (short)bf16_rne(r);
            }
            ah[g][kk] = hv; al[g][kk] = lv;
        }
        // reduce ||x||^2 partial across the 4 quads holding this row
        part += __shfl_xor(part, 16, 64);
        part += __shfl_xor(part, 32, 64);
        if (quad == 0) s_rs[wbase + g * 16 + ln] = part;
    }

    // ---- prologue: stage chunk 0 into buffer 0 ----
    uint4 ph[2], pl[2];
    float pcq = 0.f;
    #pragma unroll
    for (int i = 0; i < 2; ++i) {
        int uid = t + i * TPB;
        int code = uid >> 4, gq = uid & 15;
        ph[i] = ((const uint4*)cbh)[(size_t)code * 16 + gq];
        pl[i] = ((const uint4*)cbl)[(size_t)code * 16 + gq];
    }
    if (t < NCHUNK) pcq = cq[t] + BIGF;
    {
        uint8_t* dst = s_buf;
        #pragma unroll
        for (int i = 0; i < 2; ++i) {
            int uid = t + i * TPB;
            int code = uid >> 4, gq = uid & 15;
            *(uint4*)(dst + code * BSTRIDE + gq * 16) = ph[i];
            *(uint4*)(dst + NCHUNK * BSTRIDE + code * BSTRIDE + gq * 16) = pl[i];
        }
        if (t < NCHUNK) s_cqb[0][t] = pcq;
    }
    __syncthreads();

    // ---- packed top-3 state per (rowgroup, acc-reg) slot ----
    uint32_t p1[4][4], p2[4][4], p3[4][4];
    #pragma unroll
    for (int g = 0; g < 4; ++g)
        #pragma unroll
        for (int r = 0; r < 4; ++r) { p1[g][r] = 0xFFFFFFFFu; p2[g][r] = 0xFFFFFFFFu; p3[g][r] = 0xFFFFFFFFu; }

    #pragma unroll 1
    for (int chn = 0; chn < NCHUNKS; ++chn) {
        const int buf = chn & 1;
        // prefetch next chunk into registers (in flight across this chunk's compute)
        if (chn + 1 < NCHUNKS) {
            const int kbase = (chn + 1) * NCHUNK;
            #pragma unroll
            for (int i = 0; i < 2; ++i) {
                int uid = t + i * TPB;
                int code = uid >> 4, gq = uid & 15;
                ph[i] = ((const uint4*)cbh)[(size_t)(kbase + code) * 16 + gq];
                pl[i] = ((const uint4*)cbl)[(size_t)(kbase + code) * 16 + gq];
            }
            if (t < NCHUNK) pcq = cq[kbase + t] + BIGF;
        }

        const uint8_t* bb = s_buf + buf * CHUNK_BYTES + (size_t)ln * BSTRIDE + quad * 16;
        #pragma unroll
        for (int ct = 0; ct < 2; ++ct) {
            const uint8_t* bh_p = bb + (size_t)ct * 16 * BSTRIDE;
            const uint8_t* bl_p = bh_p + (size_t)NCHUNK * BSTRIDE;
            f32x4_t acc[4];
            #pragma unroll
            for (int g = 0; g < 4; ++g) acc[g] = (f32x4_t){0.f, 0.f, 0.f, 0.f};
            #pragma unroll
            for (int kk = 0; kk < 4; ++kk) {
                bf16x8_t bh = *(const bf16x8_t*)(bh_p + kk * 64);
                bf16x8_t bl = *(const bf16x8_t*)(bl_p + kk * 64);
                #pragma unroll
                for (int g = 0; g < 4; ++g) {
                    acc[g] = MFMA_BF16(ah[g][kk], bh, acc[g], 0, 0, 0);
                    acc[g] = MFMA_BF16(al[g][kk], bh, acc[g], 0, 0, 0);
                    acc[g] = MFMA_BF16(ah[g][kk], bl, acc[g], 0, 0, 0);
                }
            }
            const float cqv = s_cqb[buf][ct * 16 + ln];   // cq + BIG
            const uint32_t idx6 = (uint32_t)(chn * 2 + ct);
            #pragma unroll
            for (int g = 0; g < 4; ++g)
                #pragma unroll
                for (int r = 0; r < 4; ++r) {
                    float s_ = fmaf(-2.f, acc[g][r], cqv);           // s + BIG > 0 (Cauchy-Schwarz)
                    uint32_t u = (__float_as_uint(s_) & 0xFFFFFFC0u) | idx6;
                    uint32_t pm = p2[g][r];
                    uint32_t mn = u < pm ? u : pm;
                    uint32_t mx = u < pm ? pm : u;
                    uint32_t q3o = p3[g][r];
                    p3[g][r] = q3o < mx ? q3o : mx;                  // 3rd smallest
                    uint32_t q1o = p1[g][r];
                    p2[g][r] = q1o > mn ? q1o : mn;                  // 2nd smallest
                    p1[g][r] = q1o < u ? q1o : u;                    // smallest
                }
        }

        // write prefetched chunk into the other buffer (it was fully consumed last iter)
        if (chn + 1 < NCHUNKS) {
            uint8_t* dst = s_buf + (1 - buf) * CHUNK_BYTES;
            #pragma unroll
            for (int i = 0; i < 2; ++i) {
                int uid = t + i * TPB;
                int code = uid >> 4, gq = uid & 15;
                *(uint4*)(dst + code * BSTRIDE + gq * 16) = ph[i];
                *(uint4*)(dst + NCHUNK * BSTRIDE + code * BSTRIDE + gq * 16) = pl[i];
            }
            if (t < NCHUNK) s_cqb[1 - buf][t] = pcq;
        }
        __syncthreads();
    }

    // ---- unpack to (qval, full code), butterfly-merge top-3 across the 16 lanes ----
    uint32_t q[4][4][3]; int kc[4][4][3];
    #pragma unroll
    for (int g = 0; g < 4; ++g)
        #pragma unroll
        for (int r = 0; r < 4; ++r) {
            uint32_t keys[3] = {p1[g][r], p2[g][r], p3[g][r]};
            #pragma unroll
            for (int j = 0; j < 3; ++j) {
                q[g][r][j] = keys[j] & 0xFFFFFFC0u;
                int i6 = (int)(keys[j] & 63u);
                kc[g][r][j] = ((i6 >> 1) << 5) + ((i6 & 1) << 4) + ln;
            }
        }
    #pragma unroll
    for (int m = 1; m <= 8; m <<= 1) {
        #pragma unroll
        for (int g = 0; g < 4; ++g)
            #pragma unroll
            for (int r = 0; r < 4; ++r) {
                uint32_t oq0 = (uint32_t)__shfl_xor((int)q[g][r][0], m, 16);
                uint32_t oq1 = (uint32_t)__shfl_xor((int)q[g][r][1], m, 16);
                uint32_t oq2 = (uint32_t)__shfl_xor((int)q[g][r][2], m, 16);
                int ok0 = __shfl_xor(kc[g][r][0], m, 16);
                int ok1 = __shfl_xor(kc[g][r][1], m, 16);
                int ok2 = __shfl_xor(kc[g][r][2], m, 16);
                ins3(oq0, ok0, q[g][r], kc[g][r]);
                ins3(oq1, ok1, q[g][r], kc[g][r]);
                ins3(oq2, ok2, q[g][r], kc[g][r]);
            }
    }
    if (ln == 0) {
        #pragma unroll
        for (int g = 0; g < 4; ++g)
            #pragma unroll
            for (int r = 0; r < 4; ++r) {
                int row_local = wbase + g * 16 + quad * 4 + r;
                #pragma unroll
                for (int j = 0; j < 3; ++j) {
                    s_resq[row_local][j] = q[g][r][j];
                    s_resk[row_local][j] = kc[g][r][j];
                }
            }
    }
    __syncthreads();

    // ---- per-row finalize: fp64 re-decide among near-tie candidates ----
    {
        int rowg = rowblock + t;
        bool valid = rowg < rows;
        int rowc = valid ? rowg : rows - 1;
        uint32_t q0 = s_resq[t][0], q1v = s_resq[t][1], q2v = s_resq[t][2];
        int c0 = s_resk[t][0], c1 = s_resk[t][1], c2 = s_resk[t][2];
        float rsv = s_rs[t];
        float f0 = __uint_as_float(q0);
        float f1 = __uint_as_float(q1v);
        float f2 = __uint_as_float(q2v);
        int kfin = c0;
        float dfin = rsv + (f0 - BIGF);
        if (f1 - f0 < EPS_TRIG) {
            const float* xrp = x + (size_t)rowc * C;
            double best = 1e300; int bestk = 0x7fffffff;
            #pragma unroll 1
            for (int i = 0; i < 3; ++i) {
                float fi = (i == 0) ? f0 : ((i == 1) ? f1 : f2);
                int   ki = (i == 0) ? c0 : ((i == 1) ? c1 : c2);
                if (fi - f0 < EPS_TRIG) {
                    const float* cp = cb + (size_t)ki * C;
                    double dot = 0.0, cqq = 0.0;
                    #pragma unroll 8
                    for (int cc = 0; cc < C; ++cc) {
                        double xv = (double)xrp[cc], cv = (double)cp[cc];
                        dot += xv * cv; cqq += cv * cv;
                    }
                    double qd = cqq - 2.0 * dot;
                    if (qd < best || (qd == best && ki < bestk)) { best = qd; bestk = ki; }
                }
            }
            kfin = bestk;
            dfin = (float)((double)rsv + best);
        }
        if (valid) {
            out_fidx[rowg] = (float)kfin;
            out_idx[rowg]  = (float)kfin;
            out_dist[rowg] = dfin;
        }
        s_kf[t] = kfin;
    }
    __syncthreads();

    // ---- gather codes: 8 rows per iteration, 32 threads per row (coalesced) ----
    #pragma unroll 1
    for (int rr = 0; rr < ROWS_PB; rr += 8) {
        int r = rr + (t >> 5);
        int rowg2 = rowblock + r;
        if (rowg2 < rows) {
            const float4* src = (const float4*)(cb + (size_t)s_kf[r] * C);
            float4* dst = (float4*)(out_codes + (size_t)rowg2 * C);
            dst[t & 31] = src[t & 31];
        }
    }
}

// ---------------- fallback (R1 kernel, needs no workspace) ----------------
__global__ __launch_bounds__(TPB, 1)
void vq_nearest_fallback(const float* __restrict__ x,
                         const float* __restrict__ cb,
                         float* __restrict__ out_codes,
                         float* __restrict__ out_fidx,
                         float* __restrict__ out_idx,
                         float* __restrict__ out_dist,
                         int rows)
{
    __shared__ float s_cbsq[KCODES];
    const int t = threadIdx.x;
    for (int k = t; k < KCODES; k += TPB) {
        const float4* cp = (const float4*)(cb + (size_t)k * C);
        float sx = 0.f, sy = 0.f, sz = 0.f, sw = 0.f;
        #pragma unroll
        for (int i = 0; i < C / 4; ++i) {
            float4 v = cp[i];
            sx += v.x * v.x; sy += v.y * v.y; sz += v.z * v.z; sw += v.w * v.w;
        }
        s_cbsq[k] = (sx + sy) + (sz + sw);
    }
    __syncthreads();
    const int row = blockIdx.x * TPB + t;
    if (row >= rows) return;
    float xr[C];
    {
        const float4* xp = (const float4*)(x + (size_t)row * C);
        #pragma unroll
        for (int i = 0; i < C / 4; ++i) {
            float4 v = xp[i];
            xr[4*i+0] = v.x; xr[4*i+1] = v.y; xr[4*i+2] = v.z; xr[4*i+3] = v.w;
        }
    }
    float rs;
    {
        float sx = 0.f, sy = 0.f, sz = 0.f, sw = 0.f;
        #pragma unroll
        for (int i = 0; i < C / 4; ++i) {
            sx += xr[4*i+0]*xr[4*i+0]; sy += xr[4*i+1]*xr[4*i+1];
            sz += xr[4*i+2]*xr[4*i+2]; sw += xr[4*i+3]*xr[4*i+3];
        }
        rs = (sx + sy) + (sz + sw);
    }
    float v1 = INFINITY, v2 = INFINITY; int k1 = 0, k2 = 0;
    #pragma unroll 1
    for (int k0 = 0; k0 < KCODES; k0 += 4) {
        const float* c0 = cb + (size_t)k0 * C;
        float a0 = 0.f, a1 = 0.f, a2 = 0.f, a3 = 0.f;
        #pragma unroll
        for (int c = 0; c < C; ++c) {
            const float xc = xr[c];
            a0 = fmaf(xc, c0[c], a0);
            a1 = fmaf(xc, c0[C + c], a1);
            a2 = fmaf(xc, c0[2*C + c], a2);
            a3 = fmaf(xc, c0[3*C + c], a3);
        }
        const float d0 = (rs + s_cbsq[k0+0]) - 2.f * a0;
        const float d1 = (rs + s_cbsq[k0+1]) - 2.f * a1;
        const float d2 = (rs + s_cbsq[k0+2]) - 2.f * a2;
        const float d3 = (rs + s_cbsq[k0+3]) - 2.f * a3;
        #define UPDF(dv, ki)                                                 \
            if ((dv) < v1)      { v2 = v1; k2 = k1; v1 = (dv); k1 = (ki); } \
            else if ((dv) < v2) { v2 = (dv); k2 = (ki); }
        UPDF(d0, k0+0); UPDF(d1, k0+1); UPDF(d2, k0+2); UPDF(d3, k0+3);
        #undef UPDF
    }
    if (v2 - v1 < 0.125f) {
        const float* c1p = cb + (size_t)k1 * C;
        const float* c2p = cb + (size_t)k2 * C;
        double dot1 = 0.0, cq1 = 0.0, dot2 = 0.0, cq2 = 0.0;
        #pragma unroll 8
        for (int c = 0; c < C; ++c) {
            const double xc = (double)xr[c];
            const double cv1 = (double)c1p[c];
            const double cv2 = (double)c2p[c];
            dot1 += xc * cv1; cq1 += cv1 * cv1;
            dot2 += xc * cv2; cq2 += cv2 * cv2;
        }
        const double qa = cq1 - 2.0 * dot1;
        const double qb = cq2 - 2.0 * dot2;
        if (qb < qa || (qb == qa && k2 < k1)) { k1 = k2; v1 = (float)((double)rs + qb); }
    }
    {
        const float4* src = (const float4*)(cb + (size_t)k1 * C);
        float4* dst = (float4*)(out_codes + (size_t)row * C);
        #pragma unroll
        for (int i = 0; i < C / 4; ++i) dst[i] = src[i];
        out_fidx[row] = (float)k1;
        out_idx[row]  = (float)k1;
        out_dist[row] = v1;
    }
}

extern "C" void kernel_launch(void* const* d_in, const int* in_sizes, int n_in,
                              void* d_out, int out_size, void* d_ws, size_t ws_size,
                              hipStream_t stream) {
    const float* x  = (const float*)d_in[0];
    const float* cb = (const float*)d_in[1];
    const int rows = in_sizes[0] / C;   // 65536

    float* out       = (float*)d_out;
    float* out_codes = out;                          // rows*C
    float* out_fidx  = out + (size_t)rows * C;       // rows
    float* out_idx   = out_fidx + rows;              // rows
    float* out_dist  = out_idx + rows;               // rows

    // workspace layout: cbh (256KB), cbl (256KB), cq (4KB)
    const size_t cbh_off = 0;
    const size_t cbl_off = (size_t)KCODES * C * sizeof(uint16_t);
    const size_t cq_off  = cbl_off * 2;
    const size_t need    = cq_off + KCODES * sizeof(float);

    if (ws_size >= need) {
        uint16_t* cbh = (uint16_t*)((char*)d_ws + cbh_off);
        uint16_t* cbl = (uint16_t*)((char*)d_ws + cbl_off);
        float*    cq  = (float*)((char*)d_ws + cq_off);

        cb_split_kernel<<<(KCODES * C + TPB - 1) / TPB, TPB, 0, stream>>>(cb, cbh, cbl);
        cbsq_kernel<<<(KCODES + TPB - 1) / TPB, TPB, 0, stream>>>(cb, cq);

        const int grid = (rows + ROWS_PB - 1) / ROWS_PB;   // 256
        vq_mfma2_kernel<<<grid, TPB, 0, stream>>>(x, cb, cbh, cbl, cq,
                                                  out_codes, out_fidx, out_idx,
                                                  out_dist, rows);
    } else {
        const int rowblocks = (rows + TPB - 1) / TPB;
        vq_nearest_fallback<<<rowblocks, TPB, 0, stream>>>(x, cb, out_codes, out_fidx,
                                                           out_idx, out_dist, rows);
    }
}